// Round 1
// 188.958 us; speedup vs baseline: 1.0478x; 1.0478x over previous
//
#include <hip/hip_runtime.h>
#include <stdint.h>

// MultiHeadSelfAttention: E=1024, H=16, S=4096, half=512, Dh=32, scale=sqrt(64)=8
// Inputs fp32. Weights -> bf16 once; x converted inline in qkv. Double-buffered
// 128-tile MFMA GEMMs. Split-K flash attention: waves own 16 q, ones-column
// l-accumulation in MFMA. R10: P stays fully in registers -- the V tile is
// staged with a key bit-permutation p(key)=32(k>>5)+8((k>>2)&3)+4((k>>4)&1)+(k&3)
// so PV's B-fragment slot order matches the swapped-QK^T natural output order
// (keys 16t+4quad+r). Kills the Ps LDS round-trip + wave_barrier entirely, and
// the freed LDS double-buffers Ks/Vt (one barrier per K/V tile).

#define SEQ    4096
#define DMODEL 1024
#define DHALF  512
#define NH     16
#define DH     32

typedef __attribute__((ext_vector_type(4))) float facc4;
typedef __attribute__((ext_vector_type(8))) short bfrag8;

#define MFMA_BF16(a, b, c) __builtin_amdgcn_mfma_f32_16x16x32_bf16((a), (b), (c), 0, 0, 0)

static __device__ __forceinline__ uint16_t f2b(float x) {
    uint32_t u = __float_as_uint(x);
    return (uint16_t)((u + 0x7FFFu + ((u >> 16) & 1u)) >> 16);  // RNE
}
static __device__ __forceinline__ float b2f(uint16_t b) {
    return __uint_as_float(((uint32_t)b) << 16);
}

// 8x fp32 -> 8x bf16 (round-half-away; ties measure-small) via 2add+1perm pairs
static __device__ __forceinline__ bfrag8 cvt8perm(float4 a, float4 b) {
    uint32_t u0 = __float_as_uint(a.x) + 0x8000u, u1 = __float_as_uint(a.y) + 0x8000u;
    uint32_t u2 = __float_as_uint(a.z) + 0x8000u, u3 = __float_as_uint(a.w) + 0x8000u;
    uint32_t u4 = __float_as_uint(b.x) + 0x8000u, u5 = __float_as_uint(b.y) + 0x8000u;
    uint32_t u6 = __float_as_uint(b.z) + 0x8000u, u7 = __float_as_uint(b.w) + 0x8000u;
    union { uint32_t w[4]; bfrag8 r; } u;
    u.w[0] = __builtin_amdgcn_perm(u1, u0, 0x07060302u);
    u.w[1] = __builtin_amdgcn_perm(u3, u2, 0x07060302u);
    u.w[2] = __builtin_amdgcn_perm(u5, u4, 0x07060302u);
    u.w[3] = __builtin_amdgcn_perm(u7, u6, 0x07060302u);
    return u.r;
}

// Weights fp32->bf16: blocks [0,128) Wq, [128,256) Wk, [256,384) Wv, [384,640) Wo.
__global__ __launch_bounds__(256) void convert_w(
    const float* __restrict__ Wq, const float* __restrict__ Wk,
    const float* __restrict__ Wv, const float* __restrict__ Wo,
    uint16_t* __restrict__ q, uint16_t* __restrict__ k,
    uint16_t* __restrict__ v, uint16_t* __restrict__ o)
{
    int zz = blockIdx.x;
    const float* src; uint16_t* dst; size_t off;
    if      (zz < 128) { src = Wq; dst = q; off = (size_t)zz * 2048; }
    else if (zz < 256) { src = Wk; dst = k; off = (size_t)(zz - 128) * 2048; }
    else if (zz < 384) { src = Wv; dst = v; off = (size_t)(zz - 256) * 2048; }
    else               { src = Wo; dst = o; off = (size_t)(zz - 384) * 2048; }
    size_t i = off + (size_t)threadIdx.x * 8;
    float4 a = *(const float4*)&src[i];
    float4 b = *(const float4*)&src[i + 4];
    *(bfrag8*)&dst[i] = cvt8perm(a, b);
}

// ---------------------------------------------------------------------------
// 128x128-tile bf16 GEMM, double-buffered LDS (R9-verified), templated on
// whether A is fp32 (converted inline at stage time) or bf16.
// ---------------------------------------------------------------------------
template <int AF32>
__device__ __forceinline__ void gemm128T(
    const void* __restrict__ A, int lda,
    const uint16_t* __restrict__ B, int ldb,
    void* __restrict__ C, int ldc, int cF32,
    const float* __restrict__ bias, float scale,
    int Kd, int m0, int n0)
{
    __shared__ __align__(16) uint16_t As[2][128 * 40];
    __shared__ __align__(16) uint16_t Bs[2][128 * 40];

    const int tid  = threadIdx.x;
    const int lane = tid & 63;
    const int wv   = tid >> 6;
    const int lo   = lane & 15;
    const int quad = lane >> 4;
    const int srow = tid >> 2;
    const int skq  = (tid & 3) * 8;
    const int rb   = (wv >> 1) * 64;
    const int cb   = (wv & 1) * 64;

    const facc4 ZACC = {0.f, 0.f, 0.f, 0.f};
    facc4 acc[4][4];
#pragma unroll
    for (int i = 0; i < 4; ++i)
#pragma unroll
        for (int j = 0; j < 4; ++j) acc[i][j] = ZACC;

    const float*    fA0 = AF32 ? &((const float*)A)[(size_t)(m0 + srow) * lda + skq] : nullptr;
    const float*    fA1 = AF32 ? &((const float*)A)[(size_t)(m0 + srow + 64) * lda + skq] : nullptr;
    const uint16_t* hA0 = AF32 ? nullptr : &((const uint16_t*)A)[(size_t)(m0 + srow) * lda + skq];
    const uint16_t* hA1 = AF32 ? nullptr : &((const uint16_t*)A)[(size_t)(m0 + srow + 64) * lda + skq];
    const uint16_t* pB0 = &B[(size_t)(n0 + srow) * ldb + skq];
    const uint16_t* pB1 = &B[(size_t)(n0 + srow + 64) * ldb + skq];

    bfrag8 ra0, ra1;
    float4 f0a, f0b, f1a, f1b;
    if (AF32) {
        f0a = *(const float4*)fA0; f0b = *(const float4*)(fA0 + 4);
        f1a = *(const float4*)fA1; f1b = *(const float4*)(fA1 + 4);
    } else {
        ra0 = *(const bfrag8*)hA0;
        ra1 = *(const bfrag8*)hA1;
    }
    bfrag8 rb0 = *(const bfrag8*)pB0;
    bfrag8 rb1 = *(const bfrag8*)pB1;

    if (AF32) {
        *(bfrag8*)&As[0][srow * 40 + skq]        = cvt8perm(f0a, f0b);
        *(bfrag8*)&As[0][(srow + 64) * 40 + skq] = cvt8perm(f1a, f1b);
    } else {
        *(bfrag8*)&As[0][srow * 40 + skq]        = ra0;
        *(bfrag8*)&As[0][(srow + 64) * 40 + skq] = ra1;
    }
    *(bfrag8*)&Bs[0][srow * 40 + skq]        = rb0;
    *(bfrag8*)&Bs[0][(srow + 64) * 40 + skq] = rb1;
    __syncthreads();

    int p = 0;
    for (int kt = 0; kt < Kd; kt += 32) {
        const bool more = (kt + 32 < Kd);
        if (more) {  // fire-and-forget prefetch of next K-slab
            if (AF32) {
                f0a = *(const float4*)(fA0 + kt + 32); f0b = *(const float4*)(fA0 + kt + 36);
                f1a = *(const float4*)(fA1 + kt + 32); f1b = *(const float4*)(fA1 + kt + 36);
            } else {
                ra0 = *(const bfrag8*)(hA0 + kt + 32);
                ra1 = *(const bfrag8*)(hA1 + kt + 32);
            }
            rb0 = *(const bfrag8*)(pB0 + kt + 32);
            rb1 = *(const bfrag8*)(pB1 + kt + 32);
        }

        bfrag8 af[4], bf[4];
#pragma unroll
        for (int i = 0; i < 4; ++i) {
            af[i] = *(const bfrag8*)&As[p][(rb + i * 16 + lo) * 40 + quad * 8];
            bf[i] = *(const bfrag8*)&Bs[p][(cb + i * 16 + lo) * 40 + quad * 8];
        }
#pragma unroll
        for (int i = 0; i < 4; ++i)
#pragma unroll
            for (int j = 0; j < 4; ++j)
                acc[i][j] = MFMA_BF16(af[i], bf[j], acc[i][j]);

        if (more) {
            if (AF32) {
                *(bfrag8*)&As[1 - p][srow * 40 + skq]        = cvt8perm(f0a, f0b);
                *(bfrag8*)&As[1 - p][(srow + 64) * 40 + skq] = cvt8perm(f1a, f1b);
            } else {
                *(bfrag8*)&As[1 - p][srow * 40 + skq]        = ra0;
                *(bfrag8*)&As[1 - p][(srow + 64) * 40 + skq] = ra1;
            }
            *(bfrag8*)&Bs[1 - p][srow * 40 + skq]        = rb0;
            *(bfrag8*)&Bs[1 - p][(srow + 64) * 40 + skq] = rb1;
            __syncthreads();  // the only barrier per iter
            p ^= 1;
        }
    }

#pragma unroll
    for (int j = 0; j < 4; ++j) {
        int col  = n0 + cb + j * 16 + lo;
        float bv = bias ? bias[col] : 0.f;
#pragma unroll
        for (int i = 0; i < 4; ++i) {
#pragma unroll
            for (int r = 0; r < 4; ++r) {
                int row = m0 + rb + i * 16 + quad * 4 + r;
                float v = acc[i][j][r] * scale + bv;
                if (cF32) ((float*)C)[(size_t)row * ldc + col] = v;
                else      ((uint16_t*)C)[(size_t)row * ldc + col] = f2b(v);
            }
        }
    }
}

#define SC_Q (0.125f * 1.4426950408889634f)  // softmax scale * log2(e), folded into Q

// QKV from fp32 x directly (left half via lda=DMODEL, cols < 512 only).
__global__ __launch_bounds__(256, 2) void qkv_kernel(
    const float* __restrict__ x,
    const uint16_t* __restrict__ Wqb, const uint16_t* __restrict__ Wkb,
    const uint16_t* __restrict__ Wvb,
    uint16_t* __restrict__ Q, uint16_t* __restrict__ K, uint16_t* __restrict__ V)
{
    const int z = blockIdx.z;
    const uint16_t* W = (z == 0) ? Wqb : (z == 1) ? Wkb : Wvb;
    uint16_t* Out     = (z == 0) ? Q   : (z == 1) ? K   : V;
    float scale       = (z == 0) ? SC_Q : 1.0f;
    gemm128T<1>(x, DMODEL, W, DHALF, Out, DHALF, 0, nullptr, scale, DHALF,
                blockIdx.y * 128, blockIdx.x * 128);
}

__global__ __launch_bounds__(256, 2) void outproj_kernel(
    const uint16_t* __restrict__ O, const uint16_t* __restrict__ Wob,
    const float* __restrict__ bo, float* __restrict__ Y)
{
    gemm128T<0>(O, DHALF, Wob, DHALF, Y, DMODEL, 1, bo, 1.0f, DHALF,
                blockIdx.y * 128, blockIdx.x * 128);
}

// ---------------------------------------------------------------------------
// Split-K flash attention. R10: P never touches LDS.
//   QK^T (swapped, mfma(K,Q)) leaves lane (lo,quad) with P[q=lo] at keys
//   16t+4*quad+r. V is staged key-permuted: position
//   p(key) = 32*(key>>5) + 8*((key>>2)&3) + 4*((key>>4)&1) + (key&3)
//   so the unchanged vt_r reads deliver B-fragment slot j <-> key
//   32c + 16*(j>>2) + 4*quad + (j&3) -- exactly the natural pf order.
//   pf[0]=(w0,w1), pf[1]=(w2,w3) straight from the packed QK^T registers.
//   l via ones-column MFMA is key-order invariant. Freed Ps LDS double-buffers
//   Ks/Vt: one __syncthreads per K/V tile.
// ---------------------------------------------------------------------------
__global__ __launch_bounds__(256) void attn_kernel(
    const uint16_t* __restrict__ Q, const uint16_t* __restrict__ Kb,
    const uint16_t* __restrict__ Vb, uint16_t* __restrict__ Op,
    float* __restrict__ lbuf, int kspan)
{
    __shared__ __align__(16) uint16_t Ks[2][64 * 40];  // K tile [key][d]
    __shared__ __align__(16) uint16_t Vt[2][32 * 64];  // V^T [d][perm(key)], swizzled

    const int tid  = threadIdx.x;
    const int lane = tid & 63;
    const int wv   = tid >> 6;
    const int lo   = lane & 15;
    const int quad = lane >> 4;
    const int h    = blockIdx.y;
    const int q0   = blockIdx.x * 64;
    const int sp   = blockIdx.z;
    const int srow = tid >> 2;
    const int skq  = (tid & 3) * 8;

    const facc4 ZACC = {0.f, 0.f, 0.f, 0.f};

    const bfrag8 qf = *(const bfrag8*)&Q[(size_t)(q0 + wv * 16 + lo) * DHALF + h * DH + quad * 8];

    bfrag8 ones;
#pragma unroll
    for (int j = 0; j < 8; ++j) ones[j] = (short)0x3F80;  // bf16 1.0

    // V staging scatter: key srow goes to permuted column p(srow), then the
    // per-d Rd rotation (unchanged) spreads banks.
    int vt_w[8];
    {
        int pb = ((srow >> 5) << 2) | ((srow >> 2) & 3);   // p >> 3
        int pw = (((srow >> 4) & 1) << 2) | (srow & 3);    // p & 7
#pragma unroll
        for (int j = 0; j < 8; ++j) {
            int d  = skq + j;
            int Rd = ((d & 7) + 2 * (d >> 3)) & 7;
            vt_w[j] = d * 64 + (((pb + Rd) & 7) << 3) + pw;
        }
    }
    int vt_r[2][2];
#pragma unroll
    for (int dt = 0; dt < 2; ++dt) {
        int d  = dt * 16 + lo;
        int Rd = ((d & 7) + 2 * (d >> 3)) & 7;
#pragma unroll
        for (int c = 0; c < 2; ++c)
            vt_r[c][dt] = d * 64 + ((((c * 4 + quad) + Rd) & 7) << 3);
    }
    const int ks_r = lo * 40 + quad * 8;

    const uint16_t* pK = &Kb[(size_t)srow * DHALF + h * DH + skq];
    const uint16_t* pV = &Vb[(size_t)srow * DHALF + h * DH + skq];

    facc4 oacc[2], oaccL;
    oacc[0] = ZACC; oacc[1] = ZACC; oaccL = ZACC;

    const int kb0  = sp * kspan;
    const int kend = kb0 + kspan;

    float4 kreg = *(const float4*)(pK + (size_t)kb0 * DHALF);
    float4 vreg = *(const float4*)(pV + (size_t)kb0 * DHALF);

    // initial stage into buffer 0
    *(float4*)&Ks[0][srow * 40 + skq] = kreg;
    {
        const uint16_t* vp = (const uint16_t*)&vreg;
#pragma unroll
        for (int j = 0; j < 8; ++j) Vt[0][vt_w[j]] = vp[j];
    }
    __syncthreads();

    int p = 0;
    for (int kb = kb0; kb < kend; kb += 64) {
        const bool more = (kb + 64 < kend);
        if (more) {  // fire-and-forget prefetch of next K/V tile
            kreg = *(const float4*)(pK + (size_t)(kb + 64) * DHALF);
            vreg = *(const float4*)(pV + (size_t)(kb + 64) * DHALF);
        }

        // QK^T + softmax numerator, P packed to bf16 pairs in registers.
        // w[t] holds keys 16t+4*quad+{0,1} (x) and {2,3} (y) for q=lo.
        uint2 w[4];
#pragma unroll
        for (int t = 0; t < 4; ++t) {
            bfrag8 kf = *(const bfrag8*)&Ks[p][t * 640 + ks_r];
            facc4 s = MFMA_BF16(kf, qf, ZACC);  // D[key=16t+4q+r][q=lo], pre-scaled
            float p0 = __builtin_amdgcn_exp2f(s[0]);
            float p1 = __builtin_amdgcn_exp2f(s[1]);
            float p2 = __builtin_amdgcn_exp2f(s[2]);
            float p3 = __builtin_amdgcn_exp2f(s[3]);
            uint32_t u0 = __float_as_uint(p0) + 0x8000u;
            uint32_t u1 = __float_as_uint(p1) + 0x8000u;
            uint32_t u2 = __float_as_uint(p2) + 0x8000u;
            uint32_t u3 = __float_as_uint(p3) + 0x8000u;
            w[t].x = __builtin_amdgcn_perm(u1, u0, 0x07060302u);
            w[t].y = __builtin_amdgcn_perm(u3, u2, 0x07060302u);
        }

        // pf straight from registers: slot j <-> key 32c+16*(j>>2)+4*quad+(j&3)
        union PU { uint2 u2[2]; bfrag8 f; };
        PU pu0, pu1;
        pu0.u2[0] = w[0]; pu0.u2[1] = w[1];
        pu1.u2[0] = w[2]; pu1.u2[1] = w[3];

#pragma unroll
        for (int c = 0; c < 2; ++c) {
            bfrag8 pf = c ? pu1.f : pu0.f;
#pragma unroll
            for (int dt = 0; dt < 2; ++dt) {
                bfrag8 vf = *(const bfrag8*)&Vt[p][vt_r[c][dt]];
                oacc[dt] = MFMA_BF16(pf, vf, oacc[dt]);
            }
            oaccL = MFMA_BF16(pf, ones, oaccL);  // l rows: D[q][*] = sum_k P[q][k]
        }

        if (more) {  // restage into the other buffer; single barrier per iter
            *(float4*)&Ks[p ^ 1][srow * 40 + skq] = kreg;
            const uint16_t* vp = (const uint16_t*)&vreg;
#pragma unroll
            for (int j = 0; j < 8; ++j) Vt[p ^ 1][vt_w[j]] = vp[j];
            __syncthreads();
            p ^= 1;
        }
    }

    // l for q-row quad*4+r sits in oaccL[r] (same on all lo lanes)
    if (lo == 0) {
#pragma unroll
        for (int r = 0; r < 4; ++r)
            lbuf[((size_t)sp * NH + h) * SEQ + q0 + wv * 16 + quad * 4 + r] = oaccL[r];
    }

    uint16_t* Od = Op + (size_t)sp * SEQ * DHALF;
#pragma unroll
    for (int r = 0; r < 4; ++r) {
        int row = q0 + wv * 16 + quad * 4 + r;
        Od[(size_t)row * DHALF + h * DH + lo]      = f2b(oacc[0][r]);  // unnormalized
        Od[(size_t)row * DHALF + h * DH + 16 + lo] = f2b(oacc[1][r]);
    }
}

// O = sum_sp(Op_sp) / sum_sp(l_sp); 1 thread = 8 cols (within one head).
__global__ __launch_bounds__(256) void combine_kernel(
    const uint16_t* __restrict__ Op, const float* __restrict__ lbuf,
    uint16_t* __restrict__ O, int ns)
{
    int t   = blockIdx.x * 256 + threadIdx.x;
    int row = t >> 6;
    int cb  = (t & 63) << 3;
    int h   = cb >> 5;
    float l = 0.f;
    float acc[8] = {0.f, 0.f, 0.f, 0.f, 0.f, 0.f, 0.f, 0.f};
    for (int sp = 0; sp < ns; ++sp) {
        l += lbuf[((size_t)sp * NH + h) * SEQ + row];
        bfrag8 a = *(const bfrag8*)&Op[(size_t)sp * SEQ * DHALF + (size_t)row * DHALF + cb];
#pragma unroll
        for (int j = 0; j < 8; ++j) acc[j] += b2f((uint16_t)a[j]);
    }
    float inv = 1.0f / l;
    bfrag8 o;
#pragma unroll
    for (int j = 0; j < 8; ++j) o[j] = (short)f2b(acc[j] * inv);
    *(bfrag8*)&O[(size_t)row * DHALF + cb] = o;
}

extern "C" void kernel_launch(void* const* d_in, const int* in_sizes, int n_in,
                              void* d_out, int out_size, void* d_ws, size_t ws_size,
                              hipStream_t stream)
{
    const float* x  = (const float*)d_in[0];
    const float* Wq = (const float*)d_in[1];
    const float* Wk = (const float*)d_in[2];
    const float* Wv = (const float*)d_in[3];
    const float* Wo = (const float*)d_in[4];
    const float* bo = (const float*)d_in[5];

    // ws (u16 elems): Wqb/Wkb/Wvb 256K ea | Wob 512K | Q,K,V,O 2M ea | Op ns*2M
    // then lbuf (ns*NH*SEQ fp32). ns=4 needs ~37.3 MB; fall back to 2 if short.
    size_t fixed_e = 3 * (size_t)DHALF * DHALF + (size_t)DMODEL * DHALF
                   + 4 * (size_t)SEQ * DHALF;
    size_t need4 = (fixed_e + 4 * (size_t)SEQ * DHALF) * 2
                 + 4 * (size_t)NH * SEQ * 4;
    const int ns = (ws_size >= need4) ? 4 : 2;

    uint16_t* Wqb = (uint16_t*)d_ws;
    uint16_t* Wkb = Wqb + (size_t)DHALF * DHALF;
    uint16_t* Wvb = Wkb + (size_t)DHALF * DHALF;
    uint16_t* Wob = Wvb + (size_t)DHALF * DHALF;
    uint16_t* Q   = Wob + (size_t)DMODEL * DHALF;
    uint16_t* K   = Q + (size_t)SEQ * DHALF;
    uint16_t* V   = K + (size_t)SEQ * DHALF;
    uint16_t* O   = V + (size_t)SEQ * DHALF;
    uint16_t* Op  = O + (size_t)SEQ * DHALF;
    float*  lbuf  = (float*)(Op + (size_t)ns * SEQ * DHALF);

    convert_w<<<640, 256, 0, stream>>>(Wq, Wk, Wv, Wo, Wqb, Wkb, Wvb, Wob);
    qkv_kernel<<<dim3(DHALF / 128, SEQ / 128, 3), 256, 0, stream>>>(
        x, Wqb, Wkb, Wvb, Q, K, V);
    attn_kernel<<<dim3(SEQ / 64, NH, ns), 256, 0, stream>>>(Q, K, V, Op, lbuf, SEQ / ns);
    combine_kernel<<<1024, 256, 0, stream>>>(Op, lbuf, O, ns);
    outproj_kernel<<<dim3(DMODEL / 128, SEQ / 128), 256, 0, stream>>>(
        O, Wob, bo, (float*)d_out);
}

// Round 3
// 176.491 us; speedup vs baseline: 1.1218x; 1.0706x over previous
//
#include <hip/hip_runtime.h>
#include <stdint.h>

// MultiHeadSelfAttention: E=1024, H=16, S=4096, half=512, Dh=32, scale=sqrt(64)=8
// R12: R11 structure (attn waves own 32 q-rows so kf/vf LDS reads serve 2x work;
// x2-unrolled K-loop -> DS-immediate buffer offsets) with the R10-proven
// add+perm bf16 packing restored everywhere (v_cvt_pk_bf16_f32 asm was the
// R11 correctness regression). P stays in registers via key-permuted V staging.

#define SEQ    4096
#define DMODEL 1024
#define DHALF  512
#define NH     16
#define DH     32

typedef __attribute__((ext_vector_type(4))) float facc4;
typedef __attribute__((ext_vector_type(8))) short bfrag8;

#define MFMA_BF16(a, b, c) __builtin_amdgcn_mfma_f32_16x16x32_bf16((a), (b), (c), 0, 0, 0)

static __device__ __forceinline__ uint16_t f2b(float x) {
    uint32_t u = __float_as_uint(x);
    return (uint16_t)((u + 0x7FFFu + ((u >> 16) & 1u)) >> 16);  // RNE
}
static __device__ __forceinline__ float b2f(uint16_t b) {
    return __uint_as_float(((uint32_t)b) << 16);
}

// 8x fp32 -> 8x bf16 (round-half-away; ties measure-small) via 2add+1perm pairs
static __device__ __forceinline__ bfrag8 cvt8perm(float4 a, float4 b) {
    uint32_t u0 = __float_as_uint(a.x) + 0x8000u, u1 = __float_as_uint(a.y) + 0x8000u;
    uint32_t u2 = __float_as_uint(a.z) + 0x8000u, u3 = __float_as_uint(a.w) + 0x8000u;
    uint32_t u4 = __float_as_uint(b.x) + 0x8000u, u5 = __float_as_uint(b.y) + 0x8000u;
    uint32_t u6 = __float_as_uint(b.z) + 0x8000u, u7 = __float_as_uint(b.w) + 0x8000u;
    union { uint32_t w[4]; bfrag8 r; } u;
    u.w[0] = __builtin_amdgcn_perm(u1, u0, 0x07060302u);
    u.w[1] = __builtin_amdgcn_perm(u3, u2, 0x07060302u);
    u.w[2] = __builtin_amdgcn_perm(u5, u4, 0x07060302u);
    u.w[3] = __builtin_amdgcn_perm(u7, u6, 0x07060302u);
    return u.r;
}

// Weights fp32->bf16: blocks [0,128) Wq, [128,256) Wk, [256,384) Wv, [384,640) Wo.
__global__ __launch_bounds__(256) void convert_w(
    const float* __restrict__ Wq, const float* __restrict__ Wk,
    const float* __restrict__ Wv, const float* __restrict__ Wo,
    uint16_t* __restrict__ q, uint16_t* __restrict__ k,
    uint16_t* __restrict__ v, uint16_t* __restrict__ o)
{
    int zz = blockIdx.x;
    const float* src; uint16_t* dst; size_t off;
    if      (zz < 128) { src = Wq; dst = q; off = (size_t)zz * 2048; }
    else if (zz < 256) { src = Wk; dst = k; off = (size_t)(zz - 128) * 2048; }
    else if (zz < 384) { src = Wv; dst = v; off = (size_t)(zz - 256) * 2048; }
    else               { src = Wo; dst = o; off = (size_t)(zz - 384) * 2048; }
    size_t i = off + (size_t)threadIdx.x * 8;
    float4 a = *(const float4*)&src[i];
    float4 b = *(const float4*)&src[i + 4];
    *(bfrag8*)&dst[i] = cvt8perm(a, b);
}

// ---------------------------------------------------------------------------
// 128x128-tile bf16 GEMM, double-buffered LDS (R9-verified), templated on
// whether A is fp32 (converted inline at stage time) or bf16.
// ---------------------------------------------------------------------------
template <int AF32>
__device__ __forceinline__ void gemm128T(
    const void* __restrict__ A, int lda,
    const uint16_t* __restrict__ B, int ldb,
    void* __restrict__ C, int ldc, int cF32,
    const float* __restrict__ bias, float scale,
    int Kd, int m0, int n0)
{
    __shared__ __align__(16) uint16_t As[2][128 * 40];
    __shared__ __align__(16) uint16_t Bs[2][128 * 40];

    const int tid  = threadIdx.x;
    const int lane = tid & 63;
    const int wv   = tid >> 6;
    const int lo   = lane & 15;
    const int quad = lane >> 4;
    const int srow = tid >> 2;
    const int skq  = (tid & 3) * 8;
    const int rb   = (wv >> 1) * 64;
    const int cb   = (wv & 1) * 64;

    const facc4 ZACC = {0.f, 0.f, 0.f, 0.f};
    facc4 acc[4][4];
#pragma unroll
    for (int i = 0; i < 4; ++i)
#pragma unroll
        for (int j = 0; j < 4; ++j) acc[i][j] = ZACC;

    const float*    fA0 = AF32 ? &((const float*)A)[(size_t)(m0 + srow) * lda + skq] : nullptr;
    const float*    fA1 = AF32 ? &((const float*)A)[(size_t)(m0 + srow + 64) * lda + skq] : nullptr;
    const uint16_t* hA0 = AF32 ? nullptr : &((const uint16_t*)A)[(size_t)(m0 + srow) * lda + skq];
    const uint16_t* hA1 = AF32 ? nullptr : &((const uint16_t*)A)[(size_t)(m0 + srow + 64) * lda + skq];
    const uint16_t* pB0 = &B[(size_t)(n0 + srow) * ldb + skq];
    const uint16_t* pB1 = &B[(size_t)(n0 + srow + 64) * ldb + skq];

    bfrag8 ra0, ra1;
    float4 f0a, f0b, f1a, f1b;
    if (AF32) {
        f0a = *(const float4*)fA0; f0b = *(const float4*)(fA0 + 4);
        f1a = *(const float4*)fA1; f1b = *(const float4*)(fA1 + 4);
    } else {
        ra0 = *(const bfrag8*)hA0;
        ra1 = *(const bfrag8*)hA1;
    }
    bfrag8 rb0 = *(const bfrag8*)pB0;
    bfrag8 rb1 = *(const bfrag8*)pB1;

    if (AF32) {
        *(bfrag8*)&As[0][srow * 40 + skq]        = cvt8perm(f0a, f0b);
        *(bfrag8*)&As[0][(srow + 64) * 40 + skq] = cvt8perm(f1a, f1b);
    } else {
        *(bfrag8*)&As[0][srow * 40 + skq]        = ra0;
        *(bfrag8*)&As[0][(srow + 64) * 40 + skq] = ra1;
    }
    *(bfrag8*)&Bs[0][srow * 40 + skq]        = rb0;
    *(bfrag8*)&Bs[0][(srow + 64) * 40 + skq] = rb1;
    __syncthreads();

    int p = 0;
    for (int kt = 0; kt < Kd; kt += 32) {
        const bool more = (kt + 32 < Kd);
        if (more) {  // fire-and-forget prefetch of next K-slab
            if (AF32) {
                f0a = *(const float4*)(fA0 + kt + 32); f0b = *(const float4*)(fA0 + kt + 36);
                f1a = *(const float4*)(fA1 + kt + 32); f1b = *(const float4*)(fA1 + kt + 36);
            } else {
                ra0 = *(const bfrag8*)(hA0 + kt + 32);
                ra1 = *(const bfrag8*)(hA1 + kt + 32);
            }
            rb0 = *(const bfrag8*)(pB0 + kt + 32);
            rb1 = *(const bfrag8*)(pB1 + kt + 32);
        }

        bfrag8 af[4], bf[4];
#pragma unroll
        for (int i = 0; i < 4; ++i) {
            af[i] = *(const bfrag8*)&As[p][(rb + i * 16 + lo) * 40 + quad * 8];
            bf[i] = *(const bfrag8*)&Bs[p][(cb + i * 16 + lo) * 40 + quad * 8];
        }
#pragma unroll
        for (int i = 0; i < 4; ++i)
#pragma unroll
            for (int j = 0; j < 4; ++j)
                acc[i][j] = MFMA_BF16(af[i], bf[j], acc[i][j]);

        if (more) {
            if (AF32) {
                *(bfrag8*)&As[1 - p][srow * 40 + skq]        = cvt8perm(f0a, f0b);
                *(bfrag8*)&As[1 - p][(srow + 64) * 40 + skq] = cvt8perm(f1a, f1b);
            } else {
                *(bfrag8*)&As[1 - p][srow * 40 + skq]        = ra0;
                *(bfrag8*)&As[1 - p][(srow + 64) * 40 + skq] = ra1;
            }
            *(bfrag8*)&Bs[1 - p][srow * 40 + skq]        = rb0;
            *(bfrag8*)&Bs[1 - p][(srow + 64) * 40 + skq] = rb1;
            __syncthreads();  // the only barrier per iter
            p ^= 1;
        }
    }

#pragma unroll
    for (int j = 0; j < 4; ++j) {
        int col  = n0 + cb + j * 16 + lo;
        float bv = bias ? bias[col] : 0.f;
#pragma unroll
        for (int i = 0; i < 4; ++i) {
#pragma unroll
            for (int r = 0; r < 4; ++r) {
                int row = m0 + rb + i * 16 + quad * 4 + r;
                float v = acc[i][j][r] * scale + bv;
                if (cF32) ((float*)C)[(size_t)row * ldc + col] = v;
                else      ((uint16_t*)C)[(size_t)row * ldc + col] = f2b(v);
            }
        }
    }
}

#define SC_Q (0.125f * 1.4426950408889634f)  // softmax scale * log2(e), folded into Q

// QKV from fp32 x directly (left half via lda=DMODEL, cols < 512 only).
__global__ __launch_bounds__(256, 2) void qkv_kernel(
    const float* __restrict__ x,
    const uint16_t* __restrict__ Wqb, const uint16_t* __restrict__ Wkb,
    const uint16_t* __restrict__ Wvb,
    uint16_t* __restrict__ Q, uint16_t* __restrict__ K, uint16_t* __restrict__ V)
{
    const int z = blockIdx.z;
    const uint16_t* W = (z == 0) ? Wqb : (z == 1) ? Wkb : Wvb;
    uint16_t* Out     = (z == 0) ? Q   : (z == 1) ? K   : V;
    float scale       = (z == 0) ? SC_Q : 1.0f;
    gemm128T<1>(x, DMODEL, W, DHALF, Out, DHALF, 0, nullptr, scale, DHALF,
                blockIdx.y * 128, blockIdx.x * 128);
}

__global__ __launch_bounds__(256, 2) void outproj_kernel(
    const uint16_t* __restrict__ O, const uint16_t* __restrict__ Wob,
    const float* __restrict__ bo, float* __restrict__ Y)
{
    gemm128T<0>(O, DHALF, Wob, DHALF, Y, DMODEL, 1, bo, 1.0f, DHALF,
                blockIdx.y * 128, blockIdx.x * 128);
}

// ---------------------------------------------------------------------------
// Split-K flash attention. P in registers via key-permuted V staging
// (p(key)=32(k>>5)+8((k>>2)&3)+4((k>>4)&1)+(k&3)); swapped QK^T mfma(K,Q)
// gives lane (lo,quad) P[q=lo] at keys 16t+4quad+r, matching PV's B-slot order.
// Each wave owns 32 q-rows (2 qf fragments): kf/vf LDS reads serve 2x work.
// x2-unrolled K-loop makes buffer offsets DS immediates. add+perm packing.
// ---------------------------------------------------------------------------
__global__ __launch_bounds__(256) void attn_kernel(
    const uint16_t* __restrict__ Q, const uint16_t* __restrict__ Kb,
    const uint16_t* __restrict__ Vb, uint16_t* __restrict__ Op,
    float* __restrict__ lbuf, int kspan)
{
    __shared__ __align__(16) uint16_t Ks[2][64 * 40];  // K tile [key][d]
    __shared__ __align__(16) uint16_t Vt[2][32 * 64];  // V^T [d][perm(key)], swizzled

    const int tid  = threadIdx.x;
    const int lane = tid & 63;
    const int wv   = tid >> 6;
    const int lo   = lane & 15;
    const int quad = lane >> 4;
    const int h    = blockIdx.y;
    const int q0   = blockIdx.x * 128;
    const int sp   = blockIdx.z;
    const int srow = tid >> 2;
    const int skq  = (tid & 3) * 8;

    const facc4 ZACC = {0.f, 0.f, 0.f, 0.f};

    bfrag8 qf[2];
    qf[0] = *(const bfrag8*)&Q[(size_t)(q0 + wv * 32 + lo) * DHALF + h * DH + quad * 8];
    qf[1] = *(const bfrag8*)&Q[(size_t)(q0 + wv * 32 + 16 + lo) * DHALF + h * DH + quad * 8];

    bfrag8 ones;
#pragma unroll
    for (int j = 0; j < 8; ++j) ones[j] = (short)0x3F80;  // bf16 1.0

    // V staging scatter: key srow goes to permuted column p(srow), then the
    // per-d Rd rotation spreads banks.
    int vt_w[8];
    {
        int pb = ((srow >> 5) << 2) | ((srow >> 2) & 3);   // p >> 3
        int pw = (((srow >> 4) & 1) << 2) | (srow & 3);    // p & 7
#pragma unroll
        for (int j = 0; j < 8; ++j) {
            int d  = skq + j;
            int Rd = ((d & 7) + 2 * (d >> 3)) & 7;
            vt_w[j] = d * 64 + (((pb + Rd) & 7) << 3) + pw;
        }
    }
    int vt_r[2][2];
#pragma unroll
    for (int dt = 0; dt < 2; ++dt) {
        int d  = dt * 16 + lo;
        int Rd = ((d & 7) + 2 * (d >> 3)) & 7;
#pragma unroll
        for (int c = 0; c < 2; ++c)
            vt_r[c][dt] = d * 64 + ((((c * 4 + quad) + Rd) & 7) << 3);
    }
    const int ks_r = lo * 40 + quad * 8;

    const uint16_t* kp = &Kb[(size_t)(sp * kspan + srow) * DHALF + h * DH + skq];
    const uint16_t* vp = &Vb[(size_t)(sp * kspan + srow) * DHALF + h * DH + skq];

    facc4 oacc[2][2], oaccL[2];
    oacc[0][0] = ZACC; oacc[0][1] = ZACC;
    oacc[1][0] = ZACC; oacc[1][1] = ZACC;
    oaccL[0] = ZACC; oaccL[1] = ZACC;

    float4 kreg = *(const float4*)kp;
    float4 vreg = *(const float4*)vp;
    kp += 64 * DHALF;
    vp += 64 * DHALF;

#define STAGE(BUF) do {                                                       \
        *(float4*)&Ks[BUF][srow * 40 + skq] = kreg;                           \
        const uint16_t* vsp = (const uint16_t*)&vreg;                         \
        _Pragma("unroll")                                                     \
        for (int j = 0; j < 8; ++j) Vt[BUF][vt_w[j]] = vsp[j];                \
    } while (0)

#define TILE(BUF) do {                                                        \
        uint2 w0[4], w1[4];                                                   \
        _Pragma("unroll")                                                     \
        for (int t4 = 0; t4 < 4; ++t4) {                                      \
            bfrag8 kf = *(const bfrag8*)&Ks[BUF][t4 * 640 + ks_r];            \
            facc4 s0 = MFMA_BF16(kf, qf[0], ZACC);                            \
            facc4 s1 = MFMA_BF16(kf, qf[1], ZACC);                            \
            uint32_t a0 = __float_as_uint(__builtin_amdgcn_exp2f(s0[0])) + 0x8000u; \
            uint32_t a1 = __float_as_uint(__builtin_amdgcn_exp2f(s0[1])) + 0x8000u; \
            uint32_t a2 = __float_as_uint(__builtin_amdgcn_exp2f(s0[2])) + 0x8000u; \
            uint32_t a3 = __float_as_uint(__builtin_amdgcn_exp2f(s0[3])) + 0x8000u; \
            w0[t4].x = __builtin_amdgcn_perm(a1, a0, 0x07060302u);            \
            w0[t4].y = __builtin_amdgcn_perm(a3, a2, 0x07060302u);            \
            uint32_t b0 = __float_as_uint(__builtin_amdgcn_exp2f(s1[0])) + 0x8000u; \
            uint32_t b1 = __float_as_uint(__builtin_amdgcn_exp2f(s1[1])) + 0x8000u; \
            uint32_t b2 = __float_as_uint(__builtin_amdgcn_exp2f(s1[2])) + 0x8000u; \
            uint32_t b3 = __float_as_uint(__builtin_amdgcn_exp2f(s1[3])) + 0x8000u; \
            w1[t4].x = __builtin_amdgcn_perm(b1, b0, 0x07060302u);            \
            w1[t4].y = __builtin_amdgcn_perm(b3, b2, 0x07060302u);            \
        }                                                                     \
        union PU { uint2 u2[2]; bfrag8 f; } pu;                               \
        bfrag8 pf0[2], pf1[2];                                                \
        pu.u2[0] = w0[0]; pu.u2[1] = w0[1]; pf0[0] = pu.f;                    \
        pu.u2[0] = w0[2]; pu.u2[1] = w0[3]; pf0[1] = pu.f;                    \
        pu.u2[0] = w1[0]; pu.u2[1] = w1[1]; pf1[0] = pu.f;                    \
        pu.u2[0] = w1[2]; pu.u2[1] = w1[3]; pf1[1] = pu.f;                    \
        _Pragma("unroll")                                                     \
        for (int c = 0; c < 2; ++c) {                                         \
            _Pragma("unroll")                                                 \
            for (int dt = 0; dt < 2; ++dt) {                                  \
                bfrag8 vf = *(const bfrag8*)&Vt[BUF][vt_r[c][dt]];            \
                oacc[0][dt] = MFMA_BF16(pf0[c], vf, oacc[0][dt]);             \
                oacc[1][dt] = MFMA_BF16(pf1[c], vf, oacc[1][dt]);             \
            }                                                                 \
            oaccL[0] = MFMA_BF16(pf0[c], ones, oaccL[0]);                     \
            oaccL[1] = MFMA_BF16(pf1[c], ones, oaccL[1]);                     \
        }                                                                     \
    } while (0)

    // prologue: tile 0 into buffer 0
    STAGE(0);
    __syncthreads();

    const int nt = kspan >> 6;  // 16 (ns=4) or 32 (ns=2), always even
    for (int t = 0; t < nt; t += 2) {
        // tile t from buf0; prefetch t+1 (always exists: nt even)
        kreg = *(const float4*)kp;
        vreg = *(const float4*)vp;
        kp += 64 * DHALF; vp += 64 * DHALF;
        TILE(0);
        STAGE(1);
        __syncthreads();

        // tile t+1 from buf1; prefetch/restage t+2 if it exists
        const bool more = (t + 2 < nt);
        if (more) {
            kreg = *(const float4*)kp;
            vreg = *(const float4*)vp;
            kp += 64 * DHALF; vp += 64 * DHALF;
        }
        TILE(1);
        if (more) {
            STAGE(0);
            __syncthreads();
        }
    }
#undef STAGE
#undef TILE

    // l for q-row (g*16 + quad*4 + r) sits in oaccL[g][r] (same on all lo lanes)
    if (lo == 0) {
#pragma unroll
        for (int g = 0; g < 2; ++g)
#pragma unroll
            for (int r = 0; r < 4; ++r)
                lbuf[((size_t)sp * NH + h) * SEQ + q0 + wv * 32 + g * 16 + quad * 4 + r] =
                    oaccL[g][r];
    }

    uint16_t* Od = Op + (size_t)sp * SEQ * DHALF;
#pragma unroll
    for (int g = 0; g < 2; ++g) {
#pragma unroll
        for (int r = 0; r < 4; ++r) {
            int row = q0 + wv * 32 + g * 16 + quad * 4 + r;
            Od[(size_t)row * DHALF + h * DH + lo]      = f2b(oacc[g][0][r]);  // unnormalized
            Od[(size_t)row * DHALF + h * DH + 16 + lo] = f2b(oacc[g][1][r]);
        }
    }
}

// O = sum_sp(Op_sp) / sum_sp(l_sp); 1 thread = 8 cols (within one head).
__global__ __launch_bounds__(256) void combine_kernel(
    const uint16_t* __restrict__ Op, const float* __restrict__ lbuf,
    uint16_t* __restrict__ O, int ns)
{
    int t   = blockIdx.x * 256 + threadIdx.x;
    int row = t >> 6;
    int cb  = (t & 63) << 3;
    int h   = cb >> 5;
    float l = 0.f;
    float acc[8] = {0.f, 0.f, 0.f, 0.f, 0.f, 0.f, 0.f, 0.f};
    for (int sp = 0; sp < ns; ++sp) {
        l += lbuf[((size_t)sp * NH + h) * SEQ + row];
        bfrag8 a = *(const bfrag8*)&Op[(size_t)sp * SEQ * DHALF + (size_t)row * DHALF + cb];
#pragma unroll
        for (int j = 0; j < 8; ++j) acc[j] += b2f((uint16_t)a[j]);
    }
    float inv = 1.0f / l;
    bfrag8 o;
#pragma unroll
    for (int j = 0; j < 8; ++j) o[j] = (short)f2b(acc[j] * inv);
    *(bfrag8*)&O[(size_t)row * DHALF + cb] = o;
}

extern "C" void kernel_launch(void* const* d_in, const int* in_sizes, int n_in,
                              void* d_out, int out_size, void* d_ws, size_t ws_size,
                              hipStream_t stream)
{
    const float* x  = (const float*)d_in[0];
    const float* Wq = (const float*)d_in[1];
    const float* Wk = (const float*)d_in[2];
    const float* Wv = (const float*)d_in[3];
    const float* Wo = (const float*)d_in[4];
    const float* bo = (const float*)d_in[5];

    // ws (u16 elems): Wqb/Wkb/Wvb 256K ea | Wob 512K | Q,K,V,O 2M ea | Op ns*2M
    // then lbuf (ns*NH*SEQ fp32). ns=4 needs ~37.3 MB; fall back to 2 if short.
    size_t fixed_e = 3 * (size_t)DHALF * DHALF + (size_t)DMODEL * DHALF
                   + 4 * (size_t)SEQ * DHALF;
    size_t need4 = (fixed_e + 4 * (size_t)SEQ * DHALF) * 2
                 + 4 * (size_t)NH * SEQ * 4;
    const int ns = (ws_size >= need4) ? 4 : 2;

    uint16_t* Wqb = (uint16_t*)d_ws;
    uint16_t* Wkb = Wqb + (size_t)DHALF * DHALF;
    uint16_t* Wvb = Wkb + (size_t)DHALF * DHALF;
    uint16_t* Wob = Wvb + (size_t)DHALF * DHALF;
    uint16_t* Q   = Wob + (size_t)DMODEL * DHALF;
    uint16_t* K   = Q + (size_t)SEQ * DHALF;
    uint16_t* V   = K + (size_t)SEQ * DHALF;
    uint16_t* O   = V + (size_t)SEQ * DHALF;
    uint16_t* Op  = O + (size_t)SEQ * DHALF;
    float*  lbuf  = (float*)(Op + (size_t)ns * SEQ * DHALF);

    convert_w<<<640, 256, 0, stream>>>(Wq, Wk, Wv, Wo, Wqb, Wkb, Wvb, Wob);
    qkv_kernel<<<dim3(DHALF / 128, SEQ / 128, 3), 256, 0, stream>>>(
        x, Wqb, Wkb, Wvb, Q, K, V);
    attn_kernel<<<dim3(SEQ / 128, NH, ns), 256, 0, stream>>>(Q, K, V, Op, lbuf, SEQ / ns);
    combine_kernel<<<1024, 256, 0, stream>>>(Op, lbuf, O, ns);
    outproj_kernel<<<dim3(DMODEL / 128, SEQ / 128), 256, 0, stream>>>(
        O, Wob, bo, (float*)d_out);
}

// Round 4
// 175.683 us; speedup vs baseline: 1.1270x; 1.0046x over previous
//
#include <hip/hip_runtime.h>
#include <stdint.h>

// MultiHeadSelfAttention: E=1024, H=16, S=4096, half=512, Dh=32, scale=sqrt(64)=8
// R13: cross-tile pipelined attention -- PV of tile t runs during tile t+1's
// QK^T/exp (separate MFMA vs VALU pipes overlap). Vt has 4 buffers so lagged PV
// reads never race restaging; Ks keeps 2; one barrier per tile; x4-unrolled
// schedule keeps every LDS index a compile-time immediate. setprio(1) around PV.
// x converted to bf16 once in convert_w (stored in the O slot); qkv runs the
// pure-bf16 GEMM path. P stays in registers via key-permuted V staging (R10).

#define SEQ    4096
#define DMODEL 1024
#define DHALF  512
#define NH     16
#define DH     32

typedef __attribute__((ext_vector_type(4))) float facc4;
typedef __attribute__((ext_vector_type(8))) short bfrag8;

#define MFMA_BF16(a, b, c) __builtin_amdgcn_mfma_f32_16x16x32_bf16((a), (b), (c), 0, 0, 0)

static __device__ __forceinline__ uint16_t f2b(float x) {
    uint32_t u = __float_as_uint(x);
    return (uint16_t)((u + 0x7FFFu + ((u >> 16) & 1u)) >> 16);  // RNE
}
static __device__ __forceinline__ float b2f(uint16_t b) {
    return __uint_as_float(((uint32_t)b) << 16);
}

// 8x fp32 -> 8x bf16 (round-half-away; ties measure-small) via 2add+1perm pairs
static __device__ __forceinline__ bfrag8 cvt8perm(float4 a, float4 b) {
    uint32_t u0 = __float_as_uint(a.x) + 0x8000u, u1 = __float_as_uint(a.y) + 0x8000u;
    uint32_t u2 = __float_as_uint(a.z) + 0x8000u, u3 = __float_as_uint(a.w) + 0x8000u;
    uint32_t u4 = __float_as_uint(b.x) + 0x8000u, u5 = __float_as_uint(b.y) + 0x8000u;
    uint32_t u6 = __float_as_uint(b.z) + 0x8000u, u7 = __float_as_uint(b.w) + 0x8000u;
    union { uint32_t w[4]; bfrag8 r; } u;
    u.w[0] = __builtin_amdgcn_perm(u1, u0, 0x07060302u);
    u.w[1] = __builtin_amdgcn_perm(u3, u2, 0x07060302u);
    u.w[2] = __builtin_amdgcn_perm(u5, u4, 0x07060302u);
    u.w[3] = __builtin_amdgcn_perm(u7, u6, 0x07060302u);
    return u.r;
}

// Weights fp32->bf16: blocks [0,128) Wq, [128,256) Wk, [256,384) Wv, [384,640) Wo.
// Blocks [640,1664): x left-half fp32 -> xb bf16 (4096x512, row-major).
__global__ __launch_bounds__(256) void convert_w(
    const float* __restrict__ Wq, const float* __restrict__ Wk,
    const float* __restrict__ Wv, const float* __restrict__ Wo,
    const float* __restrict__ x,
    uint16_t* __restrict__ q, uint16_t* __restrict__ k,
    uint16_t* __restrict__ v, uint16_t* __restrict__ o,
    uint16_t* __restrict__ xb)
{
    int zz = blockIdx.x;
    if (zz >= 640) {
        size_t g = (size_t)(zz - 640) * 2048 + (size_t)threadIdx.x * 8;
        int row = (int)(g >> 9);
        int col = (int)(g & 511);
        const float* src = &x[(size_t)row * DMODEL + col];
        float4 a = *(const float4*)src;
        float4 b = *(const float4*)(src + 4);
        *(bfrag8*)&xb[g] = cvt8perm(a, b);
        return;
    }
    const float* src; uint16_t* dst; size_t off;
    if      (zz < 128) { src = Wq; dst = q; off = (size_t)zz * 2048; }
    else if (zz < 256) { src = Wk; dst = k; off = (size_t)(zz - 128) * 2048; }
    else if (zz < 384) { src = Wv; dst = v; off = (size_t)(zz - 256) * 2048; }
    else               { src = Wo; dst = o; off = (size_t)(zz - 384) * 2048; }
    size_t i = off + (size_t)threadIdx.x * 8;
    float4 a = *(const float4*)&src[i];
    float4 b = *(const float4*)&src[i + 4];
    *(bfrag8*)&dst[i] = cvt8perm(a, b);
}

// ---------------------------------------------------------------------------
// 128x128-tile bf16 GEMM, double-buffered LDS (R9-verified). A is bf16.
// ---------------------------------------------------------------------------
__device__ __forceinline__ void gemm128(
    const uint16_t* __restrict__ A, int lda,
    const uint16_t* __restrict__ B, int ldb,
    void* __restrict__ C, int ldc, int cF32,
    const float* __restrict__ bias, float scale,
    int Kd, int m0, int n0)
{
    __shared__ __align__(16) uint16_t As[2][128 * 40];
    __shared__ __align__(16) uint16_t Bs[2][128 * 40];

    const int tid  = threadIdx.x;
    const int lane = tid & 63;
    const int wv   = tid >> 6;
    const int lo   = lane & 15;
    const int quad = lane >> 4;
    const int srow = tid >> 2;
    const int skq  = (tid & 3) * 8;
    const int rb   = (wv >> 1) * 64;
    const int cb   = (wv & 1) * 64;

    const facc4 ZACC = {0.f, 0.f, 0.f, 0.f};
    facc4 acc[4][4];
#pragma unroll
    for (int i = 0; i < 4; ++i)
#pragma unroll
        for (int j = 0; j < 4; ++j) acc[i][j] = ZACC;

    const uint16_t* hA0 = &A[(size_t)(m0 + srow) * lda + skq];
    const uint16_t* hA1 = &A[(size_t)(m0 + srow + 64) * lda + skq];
    const uint16_t* pB0 = &B[(size_t)(n0 + srow) * ldb + skq];
    const uint16_t* pB1 = &B[(size_t)(n0 + srow + 64) * ldb + skq];

    bfrag8 ra0 = *(const bfrag8*)hA0;
    bfrag8 ra1 = *(const bfrag8*)hA1;
    bfrag8 rb0 = *(const bfrag8*)pB0;
    bfrag8 rb1 = *(const bfrag8*)pB1;

    *(bfrag8*)&As[0][srow * 40 + skq]        = ra0;
    *(bfrag8*)&As[0][(srow + 64) * 40 + skq] = ra1;
    *(bfrag8*)&Bs[0][srow * 40 + skq]        = rb0;
    *(bfrag8*)&Bs[0][(srow + 64) * 40 + skq] = rb1;
    __syncthreads();

    int p = 0;
    for (int kt = 0; kt < Kd; kt += 32) {
        const bool more = (kt + 32 < Kd);
        if (more) {  // fire-and-forget prefetch of next K-slab
            ra0 = *(const bfrag8*)(hA0 + kt + 32);
            ra1 = *(const bfrag8*)(hA1 + kt + 32);
            rb0 = *(const bfrag8*)(pB0 + kt + 32);
            rb1 = *(const bfrag8*)(pB1 + kt + 32);
        }

        bfrag8 af[4], bf[4];
#pragma unroll
        for (int i = 0; i < 4; ++i) {
            af[i] = *(const bfrag8*)&As[p][(rb + i * 16 + lo) * 40 + quad * 8];
            bf[i] = *(const bfrag8*)&Bs[p][(cb + i * 16 + lo) * 40 + quad * 8];
        }
#pragma unroll
        for (int i = 0; i < 4; ++i)
#pragma unroll
            for (int j = 0; j < 4; ++j)
                acc[i][j] = MFMA_BF16(af[i], bf[j], acc[i][j]);

        if (more) {
            *(bfrag8*)&As[1 - p][srow * 40 + skq]        = ra0;
            *(bfrag8*)&As[1 - p][(srow + 64) * 40 + skq] = ra1;
            *(bfrag8*)&Bs[1 - p][srow * 40 + skq]        = rb0;
            *(bfrag8*)&Bs[1 - p][(srow + 64) * 40 + skq] = rb1;
            __syncthreads();  // the only barrier per iter
            p ^= 1;
        }
    }

#pragma unroll
    for (int j = 0; j < 4; ++j) {
        int col  = n0 + cb + j * 16 + lo;
        float bv = bias ? bias[col] : 0.f;
#pragma unroll
        for (int i = 0; i < 4; ++i) {
#pragma unroll
            for (int r = 0; r < 4; ++r) {
                int row = m0 + rb + i * 16 + quad * 4 + r;
                float v = acc[i][j][r] * scale + bv;
                if (cF32) ((float*)C)[(size_t)row * ldc + col] = v;
                else      ((uint16_t*)C)[(size_t)row * ldc + col] = f2b(v);
            }
        }
    }
}

#define SC_Q (0.125f * 1.4426950408889634f)  // softmax scale * log2(e), folded into Q

// QKV from pre-converted bf16 xb.
__global__ __launch_bounds__(256, 2) void qkv_kernel(
    const uint16_t* __restrict__ xb,
    const uint16_t* __restrict__ Wqb, const uint16_t* __restrict__ Wkb,
    const uint16_t* __restrict__ Wvb,
    uint16_t* __restrict__ Q, uint16_t* __restrict__ K, uint16_t* __restrict__ V)
{
    const int z = blockIdx.z;
    const uint16_t* W = (z == 0) ? Wqb : (z == 1) ? Wkb : Wvb;
    uint16_t* Out     = (z == 0) ? Q   : (z == 1) ? K   : V;
    float scale       = (z == 0) ? SC_Q : 1.0f;
    gemm128(xb, DHALF, W, DHALF, Out, DHALF, 0, nullptr, scale, DHALF,
            blockIdx.y * 128, blockIdx.x * 128);
}

__global__ __launch_bounds__(256, 2) void outproj_kernel(
    const uint16_t* __restrict__ O, const uint16_t* __restrict__ Wob,
    const float* __restrict__ bo, float* __restrict__ Y)
{
    gemm128(O, DHALF, Wob, DHALF, Y, DMODEL, 1, bo, 1.0f, DHALF,
            blockIdx.y * 128, blockIdx.x * 128);
}

// ---------------------------------------------------------------------------
// Split-K flash attention, cross-tile pipelined.
//   Swapped QK^T mfma(K,Q): lane (lo,quad) holds P[q=lo] at keys 16t+4quad+r.
//   V staged key-permuted (p(key)=32(k>>5)+8((k>>2)&3)+4((k>>4)&1)+(k&3)) so
//   PV's B-slot order matches P's register order -- P never touches LDS.
//   Pipeline: QKEXP(tile u) -> pf set; PV(tile u-1) consumes the previous set
//   in the same region, so PV MFMAs overlap the exp/pack VALU chain. Ks: 2
//   buffers; Vt: 4 buffers (lagged PV read never races restage); 1 barrier
//   per tile; x4 unroll keeps all LDS offsets immediate.
// ---------------------------------------------------------------------------
__global__ __launch_bounds__(256) void attn_kernel(
    const uint16_t* __restrict__ Q, const uint16_t* __restrict__ Kb,
    const uint16_t* __restrict__ Vb, uint16_t* __restrict__ Op,
    float* __restrict__ lbuf, int kspan)
{
    __shared__ __align__(16) uint16_t Ks[2][64 * 40];  // K tile [key][d]
    __shared__ __align__(16) uint16_t Vt[4][32 * 64];  // V^T [d][perm(key)], swizzled

    const int tid  = threadIdx.x;
    const int lane = tid & 63;
    const int wv   = tid >> 6;
    const int lo   = lane & 15;
    const int quad = lane >> 4;
    const int h    = blockIdx.y;
    const int q0   = blockIdx.x * 128;
    const int sp   = blockIdx.z;
    const int srow = tid >> 2;
    const int skq  = (tid & 3) * 8;

    const facc4 ZACC = {0.f, 0.f, 0.f, 0.f};

    bfrag8 qf[2];
    qf[0] = *(const bfrag8*)&Q[(size_t)(q0 + wv * 32 + lo) * DHALF + h * DH + quad * 8];
    qf[1] = *(const bfrag8*)&Q[(size_t)(q0 + wv * 32 + 16 + lo) * DHALF + h * DH + quad * 8];

    bfrag8 ones;
#pragma unroll
    for (int j = 0; j < 8; ++j) ones[j] = (short)0x3F80;  // bf16 1.0

    // V staging scatter: key srow -> permuted column p(srow); per-d Rd rotation
    // spreads banks.
    int vt_w[8];
    {
        int pb = ((srow >> 5) << 2) | ((srow >> 2) & 3);   // p >> 3
        int pw = (((srow >> 4) & 1) << 2) | (srow & 3);    // p & 7
#pragma unroll
        for (int j = 0; j < 8; ++j) {
            int d  = skq + j;
            int Rd = ((d & 7) + 2 * (d >> 3)) & 7;
            vt_w[j] = d * 64 + (((pb + Rd) & 7) << 3) + pw;
        }
    }
    int vt_r[2][2];
#pragma unroll
    for (int dt = 0; dt < 2; ++dt) {
        int d  = dt * 16 + lo;
        int Rd = ((d & 7) + 2 * (d >> 3)) & 7;
#pragma unroll
        for (int c = 0; c < 2; ++c)
            vt_r[c][dt] = d * 64 + ((((c * 4 + quad) + Rd) & 7) << 3);
    }
    const int ks_r = lo * 40 + quad * 8;

    const uint16_t* kp = &Kb[(size_t)(sp * kspan + srow) * DHALF + h * DH + skq];
    const uint16_t* vp = &Vb[(size_t)(sp * kspan + srow) * DHALF + h * DH + skq];

    facc4 oacc[2][2], oaccL[2];
    oacc[0][0] = ZACC; oacc[0][1] = ZACC;
    oacc[1][0] = ZACC; oacc[1][1] = ZACC;
    oaccL[0] = ZACC; oaccL[1] = ZACC;

    float4 kreg, vreg;
    bfrag8 pfA0[2], pfA1[2], pfB0[2], pfB1[2];

#define LOADKV do {                                                           \
        kreg = *(const float4*)kp;                                            \
        vreg = *(const float4*)vp;                                            \
        kp += 64 * DHALF; vp += 64 * DHALF;                                   \
    } while (0)

#define STAGE(KB, VB) do {                                                    \
        *(float4*)&Ks[KB][srow * 40 + skq] = kreg;                            \
        const uint16_t* vsp = (const uint16_t*)&vreg;                         \
        _Pragma("unroll")                                                     \
        for (int j = 0; j < 8; ++j) Vt[VB][vt_w[j]] = vsp[j];                 \
    } while (0)

#define QKEXP(KB, PF0, PF1) do {                                              \
        uint2 w0[4], w1[4];                                                   \
        _Pragma("unroll")                                                     \
        for (int t4 = 0; t4 < 4; ++t4) {                                      \
            bfrag8 kf = *(const bfrag8*)&Ks[KB][t4 * 640 + ks_r];             \
            facc4 s0 = MFMA_BF16(kf, qf[0], ZACC);                            \
            facc4 s1 = MFMA_BF16(kf, qf[1], ZACC);                            \
            uint32_t a0 = __float_as_uint(__builtin_amdgcn_exp2f(s0[0])) + 0x8000u; \
            uint32_t a1 = __float_as_uint(__builtin_amdgcn_exp2f(s0[1])) + 0x8000u; \
            uint32_t a2 = __float_as_uint(__builtin_amdgcn_exp2f(s0[2])) + 0x8000u; \
            uint32_t a3 = __float_as_uint(__builtin_amdgcn_exp2f(s0[3])) + 0x8000u; \
            w0[t4].x = __builtin_amdgcn_perm(a1, a0, 0x07060302u);            \
            w0[t4].y = __builtin_amdgcn_perm(a3, a2, 0x07060302u);            \
            uint32_t b0 = __float_as_uint(__builtin_amdgcn_exp2f(s1[0])) + 0x8000u; \
            uint32_t b1 = __float_as_uint(__builtin_amdgcn_exp2f(s1[1])) + 0x8000u; \
            uint32_t b2 = __float_as_uint(__builtin_amdgcn_exp2f(s1[2])) + 0x8000u; \
            uint32_t b3 = __float_as_uint(__builtin_amdgcn_exp2f(s1[3])) + 0x8000u; \
            w1[t4].x = __builtin_amdgcn_perm(b1, b0, 0x07060302u);            \
            w1[t4].y = __builtin_amdgcn_perm(b3, b2, 0x07060302u);            \
        }                                                                     \
        union PU { uint2 u2[2]; bfrag8 f; } pu;                               \
        pu.u2[0] = w0[0]; pu.u2[1] = w0[1]; PF0[0] = pu.f;                    \
        pu.u2[0] = w0[2]; pu.u2[1] = w0[3]; PF0[1] = pu.f;                    \
        pu.u2[0] = w1[0]; pu.u2[1] = w1[1]; PF1[0] = pu.f;                    \
        pu.u2[0] = w1[2]; pu.u2[1] = w1[3]; PF1[1] = pu.f;                    \
    } while (0)

#define PV(VB, PF0, PF1) do {                                                 \
        __builtin_amdgcn_s_setprio(1);                                        \
        _Pragma("unroll")                                                     \
        for (int c = 0; c < 2; ++c) {                                         \
            _Pragma("unroll")                                                 \
            for (int dt = 0; dt < 2; ++dt) {                                  \
                bfrag8 vf = *(const bfrag8*)&Vt[VB][vt_r[c][dt]];             \
                oacc[0][dt] = MFMA_BF16(PF0[c], vf, oacc[0][dt]);             \
                oacc[1][dt] = MFMA_BF16(PF1[c], vf, oacc[1][dt]);             \
            }                                                                 \
            oaccL[0] = MFMA_BF16(PF0[c], ones, oaccL[0]);                     \
            oaccL[1] = MFMA_BF16(PF1[c], ones, oaccL[1]);                     \
        }                                                                     \
        __builtin_amdgcn_s_setprio(0);                                        \
    } while (0)

    const int nt = kspan >> 6;  // 16 (ns=4) or 32 (ns=2); multiple of 4, >= 16

    // Prologue group: tiles 0..3 (PV omitted at tile 0; nt >= 16 so no guards).
    LOADKV;                                   // tile 0
    STAGE(0, 0);
    __syncthreads();
    LOADKV;                                   // tile 1
    QKEXP(0, pfA0, pfA1);                     // tile 0
    STAGE(1, 1); __syncthreads(); LOADKV;     // stage t1, load tile 2
    QKEXP(1, pfB0, pfB1);                     // tile 1
    PV(0, pfA0, pfA1);                        // tile 0
    STAGE(0, 2); __syncthreads(); LOADKV;     // stage t2, load tile 3
    QKEXP(0, pfA0, pfA1);                     // tile 2
    PV(1, pfB0, pfB1);                        // tile 1
    STAGE(1, 3); __syncthreads(); LOADKV;     // stage t3, load tile 4
    QKEXP(1, pfB0, pfB1);                     // tile 3
    PV(2, pfA0, pfA1);                        // tile 2
    STAGE(0, 0); __syncthreads(); LOADKV;     // stage t4, load tile 5

    for (int t = 4; t < nt; t += 4) {
        // entering: tile t staged in (Ks0, Vt0); kreg/vreg = tile t+1
        QKEXP(0, pfA0, pfA1);                 // tile t
        PV(3, pfB0, pfB1);                    // tile t-1
        STAGE(1, 1); __syncthreads(); LOADKV; // stage t+1, load t+2

        QKEXP(1, pfB0, pfB1);                 // tile t+1
        PV(0, pfA0, pfA1);                    // tile t
        STAGE(0, 2); __syncthreads(); LOADKV; // stage t+2, load t+3

        QKEXP(0, pfA0, pfA1);                 // tile t+2
        PV(1, pfB0, pfB1);                    // tile t+1
        STAGE(1, 3); __syncthreads();         // stage t+3
        const bool more = (t + 4 < nt);
        if (more) LOADKV;                     // load t+4

        QKEXP(1, pfB0, pfB1);                 // tile t+3
        PV(2, pfA0, pfA1);                    // tile t+2
        if (more) {
            STAGE(0, 0); __syncthreads(); LOADKV;  // stage t+4, load t+5
        }
    }
    PV(3, pfB0, pfB1);                        // tile nt-1

#undef LOADKV
#undef STAGE
#undef QKEXP
#undef PV

    // l for q-row (g*16 + quad*4 + r) sits in oaccL[g][r] (same on all lo lanes)
    if (lo == 0) {
#pragma unroll
        for (int g = 0; g < 2; ++g)
#pragma unroll
            for (int r = 0; r < 4; ++r)
                lbuf[((size_t)sp * NH + h) * SEQ + q0 + wv * 32 + g * 16 + quad * 4 + r] =
                    oaccL[g][r];
    }

    uint16_t* Od = Op + (size_t)sp * SEQ * DHALF;
#pragma unroll
    for (int g = 0; g < 2; ++g) {
#pragma unroll
        for (int r = 0; r < 4; ++r) {
            int row = q0 + wv * 32 + g * 16 + quad * 4 + r;
            Od[(size_t)row * DHALF + h * DH + lo]      = f2b(oacc[g][0][r]);  // unnormalized
            Od[(size_t)row * DHALF + h * DH + 16 + lo] = f2b(oacc[g][1][r]);
        }
    }
}

// O = sum_sp(Op_sp) / sum_sp(l_sp); 1 thread = 8 cols (within one head).
__global__ __launch_bounds__(256) void combine_kernel(
    const uint16_t* __restrict__ Op, const float* __restrict__ lbuf,
    uint16_t* __restrict__ O, int ns)
{
    int t   = blockIdx.x * 256 + threadIdx.x;
    int row = t >> 6;
    int cb  = (t & 63) << 3;
    int h   = cb >> 5;
    float l = 0.f;
    float acc[8] = {0.f, 0.f, 0.f, 0.f, 0.f, 0.f, 0.f, 0.f};
    for (int sp = 0; sp < ns; ++sp) {
        l += lbuf[((size_t)sp * NH + h) * SEQ + row];
        bfrag8 a = *(const bfrag8*)&Op[(size_t)sp * SEQ * DHALF + (size_t)row * DHALF + cb];
#pragma unroll
        for (int j = 0; j < 8; ++j) acc[j] += b2f((uint16_t)a[j]);
    }
    float inv = 1.0f / l;
    bfrag8 o;
#pragma unroll
    for (int j = 0; j < 8; ++j) o[j] = (short)f2b(acc[j] * inv);
    *(bfrag8*)&O[(size_t)row * DHALF + cb] = o;
}

extern "C" void kernel_launch(void* const* d_in, const int* in_sizes, int n_in,
                              void* d_out, int out_size, void* d_ws, size_t ws_size,
                              hipStream_t stream)
{
    const float* x  = (const float*)d_in[0];
    const float* Wq = (const float*)d_in[1];
    const float* Wk = (const float*)d_in[2];
    const float* Wv = (const float*)d_in[3];
    const float* Wo = (const float*)d_in[4];
    const float* bo = (const float*)d_in[5];

    // ws (u16 elems): Wqb/Wkb/Wvb 256K ea | Wob 512K | Q,K,V,O 2M ea | Op ns*2M
    // then lbuf (ns*NH*SEQ fp32). xb (bf16 x left half) aliases the O slot:
    // written by convert_w, read by qkv, dead before combine writes O.
    size_t fixed_e = 3 * (size_t)DHALF * DHALF + (size_t)DMODEL * DHALF
                   + 4 * (size_t)SEQ * DHALF;
    size_t need4 = (fixed_e + 4 * (size_t)SEQ * DHALF) * 2
                 + 4 * (size_t)NH * SEQ * 4;
    const int ns = (ws_size >= need4) ? 4 : 2;

    uint16_t* Wqb = (uint16_t*)d_ws;
    uint16_t* Wkb = Wqb + (size_t)DHALF * DHALF;
    uint16_t* Wvb = Wkb + (size_t)DHALF * DHALF;
    uint16_t* Wob = Wvb + (size_t)DHALF * DHALF;
    uint16_t* Q   = Wob + (size_t)DMODEL * DHALF;
    uint16_t* K   = Q + (size_t)SEQ * DHALF;
    uint16_t* V   = K + (size_t)SEQ * DHALF;
    uint16_t* O   = V + (size_t)SEQ * DHALF;
    uint16_t* Op  = O + (size_t)SEQ * DHALF;
    float*  lbuf  = (float*)(Op + (size_t)ns * SEQ * DHALF);
    uint16_t* xb  = O;  // alias: live only convert_w -> qkv

    convert_w<<<1664, 256, 0, stream>>>(Wq, Wk, Wv, Wo, x, Wqb, Wkb, Wvb, Wob, xb);
    qkv_kernel<<<dim3(DHALF / 128, SEQ / 128, 3), 256, 0, stream>>>(
        xb, Wqb, Wkb, Wvb, Q, K, V);
    attn_kernel<<<dim3(SEQ / 128, NH, ns), 256, 0, stream>>>(Q, K, V, Op, lbuf, SEQ / ns);
    combine_kernel<<<1024, 256, 0, stream>>>(Op, lbuf, O, ns);
    outproj_kernel<<<dim3(DMODEL / 128, SEQ / 128), 256, 0, stream>>>(
        O, Wob, bo, (float*)d_out);
}

// Round 5
// 169.197 us; speedup vs baseline: 1.1702x; 1.0383x over previous
//
#include <hip/hip_runtime.h>
#include <stdint.h>

// MultiHeadSelfAttention: E=1024, H=16, S=4096, half=512, Dh=32, scale=sqrt(64)=8
// R14: attn reverted to the R12-proven structure (2-buffer Ks/Vt, x2-unrolled
// K-loop, no intra-wave pipeline -- R13 showed inter-wave overlap already covers
// it and the extra regs/LDS cost occupancy). NEW: XCD-aware panel swizzle --
// the 32 blocks sharing one (head,split) K/V panel map to the same dispatch
// residue mod 8 (= same XCD under round-robin), so each panel is fetched into
// one L2 instead of eight. bf16 x (xb) + pure-bf16 qkv kept from R13.
// P stays in registers via key-permuted V staging (R10).

#define SEQ    4096
#define DMODEL 1024
#define DHALF  512
#define NH     16
#define DH     32

typedef __attribute__((ext_vector_type(4))) float facc4;
typedef __attribute__((ext_vector_type(8))) short bfrag8;

#define MFMA_BF16(a, b, c) __builtin_amdgcn_mfma_f32_16x16x32_bf16((a), (b), (c), 0, 0, 0)

static __device__ __forceinline__ uint16_t f2b(float x) {
    uint32_t u = __float_as_uint(x);
    return (uint16_t)((u + 0x7FFFu + ((u >> 16) & 1u)) >> 16);  // RNE
}
static __device__ __forceinline__ float b2f(uint16_t b) {
    return __uint_as_float(((uint32_t)b) << 16);
}

// 8x fp32 -> 8x bf16 (round-half-away; ties measure-small) via 2add+1perm pairs
static __device__ __forceinline__ bfrag8 cvt8perm(float4 a, float4 b) {
    uint32_t u0 = __float_as_uint(a.x) + 0x8000u, u1 = __float_as_uint(a.y) + 0x8000u;
    uint32_t u2 = __float_as_uint(a.z) + 0x8000u, u3 = __float_as_uint(a.w) + 0x8000u;
    uint32_t u4 = __float_as_uint(b.x) + 0x8000u, u5 = __float_as_uint(b.y) + 0x8000u;
    uint32_t u6 = __float_as_uint(b.z) + 0x8000u, u7 = __float_as_uint(b.w) + 0x8000u;
    union { uint32_t w[4]; bfrag8 r; } u;
    u.w[0] = __builtin_amdgcn_perm(u1, u0, 0x07060302u);
    u.w[1] = __builtin_amdgcn_perm(u3, u2, 0x07060302u);
    u.w[2] = __builtin_amdgcn_perm(u5, u4, 0x07060302u);
    u.w[3] = __builtin_amdgcn_perm(u7, u6, 0x07060302u);
    return u.r;
}

// Weights fp32->bf16: blocks [0,128) Wq, [128,256) Wk, [256,384) Wv, [384,640) Wo.
// Blocks [640,1664): x left-half fp32 -> xb bf16 (4096x512, row-major).
__global__ __launch_bounds__(256) void convert_w(
    const float* __restrict__ Wq, const float* __restrict__ Wk,
    const float* __restrict__ Wv, const float* __restrict__ Wo,
    const float* __restrict__ x,
    uint16_t* __restrict__ q, uint16_t* __restrict__ k,
    uint16_t* __restrict__ v, uint16_t* __restrict__ o,
    uint16_t* __restrict__ xb)
{
    int zz = blockIdx.x;
    if (zz >= 640) {
        size_t g = (size_t)(zz - 640) * 2048 + (size_t)threadIdx.x * 8;
        int row = (int)(g >> 9);
        int col = (int)(g & 511);
        const float* src = &x[(size_t)row * DMODEL + col];
        float4 a = *(const float4*)src;
        float4 b = *(const float4*)(src + 4);
        *(bfrag8*)&xb[g] = cvt8perm(a, b);
        return;
    }
    const float* src; uint16_t* dst; size_t off;
    if      (zz < 128) { src = Wq; dst = q; off = (size_t)zz * 2048; }
    else if (zz < 256) { src = Wk; dst = k; off = (size_t)(zz - 128) * 2048; }
    else if (zz < 384) { src = Wv; dst = v; off = (size_t)(zz - 256) * 2048; }
    else               { src = Wo; dst = o; off = (size_t)(zz - 384) * 2048; }
    size_t i = off + (size_t)threadIdx.x * 8;
    float4 a = *(const float4*)&src[i];
    float4 b = *(const float4*)&src[i + 4];
    *(bfrag8*)&dst[i] = cvt8perm(a, b);
}

// ---------------------------------------------------------------------------
// 128x128-tile bf16 GEMM, double-buffered LDS (R9-verified). A is bf16.
// ---------------------------------------------------------------------------
__device__ __forceinline__ void gemm128(
    const uint16_t* __restrict__ A, int lda,
    const uint16_t* __restrict__ B, int ldb,
    void* __restrict__ C, int ldc, int cF32,
    const float* __restrict__ bias, float scale,
    int Kd, int m0, int n0)
{
    __shared__ __align__(16) uint16_t As[2][128 * 40];
    __shared__ __align__(16) uint16_t Bs[2][128 * 40];

    const int tid  = threadIdx.x;
    const int lane = tid & 63;
    const int wv   = tid >> 6;
    const int lo   = lane & 15;
    const int quad = lane >> 4;
    const int srow = tid >> 2;
    const int skq  = (tid & 3) * 8;
    const int rb   = (wv >> 1) * 64;
    const int cb   = (wv & 1) * 64;

    const facc4 ZACC = {0.f, 0.f, 0.f, 0.f};
    facc4 acc[4][4];
#pragma unroll
    for (int i = 0; i < 4; ++i)
#pragma unroll
        for (int j = 0; j < 4; ++j) acc[i][j] = ZACC;

    const uint16_t* hA0 = &A[(size_t)(m0 + srow) * lda + skq];
    const uint16_t* hA1 = &A[(size_t)(m0 + srow + 64) * lda + skq];
    const uint16_t* pB0 = &B[(size_t)(n0 + srow) * ldb + skq];
    const uint16_t* pB1 = &B[(size_t)(n0 + srow + 64) * ldb + skq];

    bfrag8 ra0 = *(const bfrag8*)hA0;
    bfrag8 ra1 = *(const bfrag8*)hA1;
    bfrag8 rb0 = *(const bfrag8*)pB0;
    bfrag8 rb1 = *(const bfrag8*)pB1;

    *(bfrag8*)&As[0][srow * 40 + skq]        = ra0;
    *(bfrag8*)&As[0][(srow + 64) * 40 + skq] = ra1;
    *(bfrag8*)&Bs[0][srow * 40 + skq]        = rb0;
    *(bfrag8*)&Bs[0][(srow + 64) * 40 + skq] = rb1;
    __syncthreads();

    int p = 0;
    for (int kt = 0; kt < Kd; kt += 32) {
        const bool more = (kt + 32 < Kd);
        if (more) {  // fire-and-forget prefetch of next K-slab
            ra0 = *(const bfrag8*)(hA0 + kt + 32);
            ra1 = *(const bfrag8*)(hA1 + kt + 32);
            rb0 = *(const bfrag8*)(pB0 + kt + 32);
            rb1 = *(const bfrag8*)(pB1 + kt + 32);
        }

        bfrag8 af[4], bf[4];
#pragma unroll
        for (int i = 0; i < 4; ++i) {
            af[i] = *(const bfrag8*)&As[p][(rb + i * 16 + lo) * 40 + quad * 8];
            bf[i] = *(const bfrag8*)&Bs[p][(cb + i * 16 + lo) * 40 + quad * 8];
        }
#pragma unroll
        for (int i = 0; i < 4; ++i)
#pragma unroll
            for (int j = 0; j < 4; ++j)
                acc[i][j] = MFMA_BF16(af[i], bf[j], acc[i][j]);

        if (more) {
            *(bfrag8*)&As[1 - p][srow * 40 + skq]        = ra0;
            *(bfrag8*)&As[1 - p][(srow + 64) * 40 + skq] = ra1;
            *(bfrag8*)&Bs[1 - p][srow * 40 + skq]        = rb0;
            *(bfrag8*)&Bs[1 - p][(srow + 64) * 40 + skq] = rb1;
            __syncthreads();  // the only barrier per iter
            p ^= 1;
        }
    }

#pragma unroll
    for (int j = 0; j < 4; ++j) {
        int col  = n0 + cb + j * 16 + lo;
        float bv = bias ? bias[col] : 0.f;
#pragma unroll
        for (int i = 0; i < 4; ++i) {
#pragma unroll
            for (int r = 0; r < 4; ++r) {
                int row = m0 + rb + i * 16 + quad * 4 + r;
                float v = acc[i][j][r] * scale + bv;
                if (cF32) ((float*)C)[(size_t)row * ldc + col] = v;
                else      ((uint16_t*)C)[(size_t)row * ldc + col] = f2b(v);
            }
        }
    }
}

#define SC_Q (0.125f * 1.4426950408889634f)  // softmax scale * log2(e), folded into Q

// QKV from pre-converted bf16 xb.
__global__ __launch_bounds__(256, 2) void qkv_kernel(
    const uint16_t* __restrict__ xb,
    const uint16_t* __restrict__ Wqb, const uint16_t* __restrict__ Wkb,
    const uint16_t* __restrict__ Wvb,
    uint16_t* __restrict__ Q, uint16_t* __restrict__ K, uint16_t* __restrict__ V)
{
    const int z = blockIdx.z;
    const uint16_t* W = (z == 0) ? Wqb : (z == 1) ? Wkb : Wvb;
    uint16_t* Out     = (z == 0) ? Q   : (z == 1) ? K   : V;
    float scale       = (z == 0) ? SC_Q : 1.0f;
    gemm128(xb, DHALF, W, DHALF, Out, DHALF, 0, nullptr, scale, DHALF,
            blockIdx.y * 128, blockIdx.x * 128);
}

__global__ __launch_bounds__(256, 2) void outproj_kernel(
    const uint16_t* __restrict__ O, const uint16_t* __restrict__ Wob,
    const float* __restrict__ bo, float* __restrict__ Y)
{
    gemm128(O, DHALF, Wob, DHALF, Y, DMODEL, 1, bo, 1.0f, DHALF,
            blockIdx.y * 128, blockIdx.x * 128);
}

// ---------------------------------------------------------------------------
// Split-K flash attention (R12 structure). P in registers via key-permuted V
// staging (p(key)=32(k>>5)+8((k>>2)&3)+4((k>>4)&1)+(k&3)); swapped QK^T
// mfma(K,Q) gives lane (lo,quad) P[q=lo] at keys 16t+4quad+r, matching PV's
// B-slot order. Waves own 32 q-rows; x2-unrolled K-loop -> DS immediates.
// R14: XCD panel swizzle -- flat block id f remapped bijectively so the 32
// blocks sharing one (h,sp) K/V panel land in one dispatch-residue class
// mod 8 (one XCD's L2 fetches the panel once).
// ---------------------------------------------------------------------------
__global__ __launch_bounds__(256) void attn_kernel(
    const uint16_t* __restrict__ Q, const uint16_t* __restrict__ Kb,
    const uint16_t* __restrict__ Vb, uint16_t* __restrict__ Op,
    float* __restrict__ lbuf, int kspan)
{
    __shared__ __align__(16) uint16_t Ks[2][64 * 40];  // K tile [key][d]
    __shared__ __align__(16) uint16_t Vt[2][32 * 64];  // V^T [d][perm(key)], swizzled

    const int tid  = threadIdx.x;
    const int lane = tid & 63;
    const int wv   = tid >> 6;
    const int lo   = lane & 15;
    const int quad = lane >> 4;

    // XCD panel swizzle: f = bx + 32*by + 512*bz; p = (f&7)|((f>>8)<<3);
    // j = (f>>3)&31. Inverse: f = (p&7) + 8*j + 256*(p>>3) -- bijective for
    // gridDim.z in {2,4}. All 32 blocks of panel p share f mod 8.
    const int f  = blockIdx.x + 32 * blockIdx.y + 512 * blockIdx.z;
    const int pp = (f & 7) | ((f >> 8) << 3);
    const int h  = pp & 15;
    const int sp = pp >> 4;
    const int q0 = ((f >> 3) & 31) * 128;

    const int srow = tid >> 2;
    const int skq  = (tid & 3) * 8;

    const facc4 ZACC = {0.f, 0.f, 0.f, 0.f};

    bfrag8 qf[2];
    qf[0] = *(const bfrag8*)&Q[(size_t)(q0 + wv * 32 + lo) * DHALF + h * DH + quad * 8];
    qf[1] = *(const bfrag8*)&Q[(size_t)(q0 + wv * 32 + 16 + lo) * DHALF + h * DH + quad * 8];

    bfrag8 ones;
#pragma unroll
    for (int j = 0; j < 8; ++j) ones[j] = (short)0x3F80;  // bf16 1.0

    // V staging scatter: key srow -> permuted column p(srow); per-d Rd rotation
    // spreads banks.
    int vt_w[8];
    {
        int pb = ((srow >> 5) << 2) | ((srow >> 2) & 3);   // p >> 3
        int pw = (((srow >> 4) & 1) << 2) | (srow & 3);    // p & 7
#pragma unroll
        for (int j = 0; j < 8; ++j) {
            int d  = skq + j;
            int Rd = ((d & 7) + 2 * (d >> 3)) & 7;
            vt_w[j] = d * 64 + (((pb + Rd) & 7) << 3) + pw;
        }
    }
    int vt_r[2][2];
#pragma unroll
    for (int dt = 0; dt < 2; ++dt) {
        int d  = dt * 16 + lo;
        int Rd = ((d & 7) + 2 * (d >> 3)) & 7;
#pragma unroll
        for (int c = 0; c < 2; ++c)
            vt_r[c][dt] = d * 64 + ((((c * 4 + quad) + Rd) & 7) << 3);
    }
    const int ks_r = lo * 40 + quad * 8;

    const uint16_t* kp = &Kb[(size_t)(sp * kspan + srow) * DHALF + h * DH + skq];
    const uint16_t* vp = &Vb[(size_t)(sp * kspan + srow) * DHALF + h * DH + skq];

    facc4 oacc[2][2], oaccL[2];
    oacc[0][0] = ZACC; oacc[0][1] = ZACC;
    oacc[1][0] = ZACC; oacc[1][1] = ZACC;
    oaccL[0] = ZACC; oaccL[1] = ZACC;

    float4 kreg = *(const float4*)kp;
    float4 vreg = *(const float4*)vp;
    kp += 64 * DHALF;
    vp += 64 * DHALF;

#define STAGE(BUF) do {                                                       \
        *(float4*)&Ks[BUF][srow * 40 + skq] = kreg;                           \
        const uint16_t* vsp = (const uint16_t*)&vreg;                         \
        _Pragma("unroll")                                                     \
        for (int j = 0; j < 8; ++j) Vt[BUF][vt_w[j]] = vsp[j];                \
    } while (0)

#define TILE(BUF) do {                                                        \
        uint2 w0[4], w1[4];                                                   \
        _Pragma("unroll")                                                     \
        for (int t4 = 0; t4 < 4; ++t4) {                                      \
            bfrag8 kf = *(const bfrag8*)&Ks[BUF][t4 * 640 + ks_r];            \
            facc4 s0 = MFMA_BF16(kf, qf[0], ZACC);                            \
            facc4 s1 = MFMA_BF16(kf, qf[1], ZACC);                            \
            uint32_t a0 = __float_as_uint(__builtin_amdgcn_exp2f(s0[0])) + 0x8000u; \
            uint32_t a1 = __float_as_uint(__builtin_amdgcn_exp2f(s0[1])) + 0x8000u; \
            uint32_t a2 = __float_as_uint(__builtin_amdgcn_exp2f(s0[2])) + 0x8000u; \
            uint32_t a3 = __float_as_uint(__builtin_amdgcn_exp2f(s0[3])) + 0x8000u; \
            w0[t4].x = __builtin_amdgcn_perm(a1, a0, 0x07060302u);            \
            w0[t4].y = __builtin_amdgcn_perm(a3, a2, 0x07060302u);            \
            uint32_t b0 = __float_as_uint(__builtin_amdgcn_exp2f(s1[0])) + 0x8000u; \
            uint32_t b1 = __float_as_uint(__builtin_amdgcn_exp2f(s1[1])) + 0x8000u; \
            uint32_t b2 = __float_as_uint(__builtin_amdgcn_exp2f(s1[2])) + 0x8000u; \
            uint32_t b3 = __float_as_uint(__builtin_amdgcn_exp2f(s1[3])) + 0x8000u; \
            w1[t4].x = __builtin_amdgcn_perm(b1, b0, 0x07060302u);            \
            w1[t4].y = __builtin_amdgcn_perm(b3, b2, 0x07060302u);            \
        }                                                                     \
        union PU { uint2 u2[2]; bfrag8 f; } pu;                               \
        bfrag8 pf0[2], pf1[2];                                                \
        pu.u2[0] = w0[0]; pu.u2[1] = w0[1]; pf0[0] = pu.f;                    \
        pu.u2[0] = w0[2]; pu.u2[1] = w0[3]; pf0[1] = pu.f;                    \
        pu.u2[0] = w1[0]; pu.u2[1] = w1[1]; pf1[0] = pu.f;                    \
        pu.u2[0] = w1[2]; pu.u2[1] = w1[3]; pf1[1] = pu.f;                    \
        _Pragma("unroll")                                                     \
        for (int c = 0; c < 2; ++c) {                                         \
            _Pragma("unroll")                                                 \
            for (int dt = 0; dt < 2; ++dt) {                                  \
                bfrag8 vf = *(const bfrag8*)&Vt[BUF][vt_r[c][dt]];            \
                oacc[0][dt] = MFMA_BF16(pf0[c], vf, oacc[0][dt]);             \
                oacc[1][dt] = MFMA_BF16(pf1[c], vf, oacc[1][dt]);             \
            }                                                                 \
            oaccL[0] = MFMA_BF16(pf0[c], ones, oaccL[0]);                     \
            oaccL[1] = MFMA_BF16(pf1[c], ones, oaccL[1]);                     \
        }                                                                     \
    } while (0)

    // prologue: tile 0 into buffer 0
    STAGE(0);
    __syncthreads();

    const int nt = kspan >> 6;  // 16 (ns=4) or 32 (ns=2), always even
    for (int t = 0; t < nt; t += 2) {
        // tile t from buf0; prefetch t+1 (always exists: nt even)
        kreg = *(const float4*)kp;
        vreg = *(const float4*)vp;
        kp += 64 * DHALF; vp += 64 * DHALF;
        TILE(0);
        STAGE(1);
        __syncthreads();

        // tile t+1 from buf1; prefetch/restage t+2 if it exists
        const bool more = (t + 2 < nt);
        if (more) {
            kreg = *(const float4*)kp;
            vreg = *(const float4*)vp;
            kp += 64 * DHALF; vp += 64 * DHALF;
        }
        TILE(1);
        if (more) {
            STAGE(0);
            __syncthreads();
        }
    }
#undef STAGE
#undef TILE

    // l for q-row (g*16 + quad*4 + r) sits in oaccL[g][r] (same on all lo lanes)
    if (lo == 0) {
#pragma unroll
        for (int g = 0; g < 2; ++g)
#pragma unroll
            for (int r = 0; r < 4; ++r)
                lbuf[((size_t)sp * NH + h) * SEQ + q0 + wv * 32 + g * 16 + quad * 4 + r] =
                    oaccL[g][r];
    }

    uint16_t* Od = Op + (size_t)sp * SEQ * DHALF;
#pragma unroll
    for (int g = 0; g < 2; ++g) {
#pragma unroll
        for (int r = 0; r < 4; ++r) {
            int row = q0 + wv * 32 + g * 16 + quad * 4 + r;
            Od[(size_t)row * DHALF + h * DH + lo]      = f2b(oacc[g][0][r]);  // unnormalized
            Od[(size_t)row * DHALF + h * DH + 16 + lo] = f2b(oacc[g][1][r]);
        }
    }
}

// O = sum_sp(Op_sp) / sum_sp(l_sp); 1 thread = 8 cols (within one head).
__global__ __launch_bounds__(256) void combine_kernel(
    const uint16_t* __restrict__ Op, const float* __restrict__ lbuf,
    uint16_t* __restrict__ O, int ns)
{
    int t   = blockIdx.x * 256 + threadIdx.x;
    int row = t >> 6;
    int cb  = (t & 63) << 3;
    int h   = cb >> 5;
    float l = 0.f;
    float acc[8] = {0.f, 0.f, 0.f, 0.f, 0.f, 0.f, 0.f, 0.f};
    for (int sp = 0; sp < ns; ++sp) {
        l += lbuf[((size_t)sp * NH + h) * SEQ + row];
        bfrag8 a = *(const bfrag8*)&Op[(size_t)sp * SEQ * DHALF + (size_t)row * DHALF + cb];
#pragma unroll
        for (int j = 0; j < 8; ++j) acc[j] += b2f((uint16_t)a[j]);
    }
    float inv = 1.0f / l;
    bfrag8 o;
#pragma unroll
    for (int j = 0; j < 8; ++j) o[j] = (short)f2b(acc[j] * inv);
    *(bfrag8*)&O[(size_t)row * DHALF + cb] = o;
}

extern "C" void kernel_launch(void* const* d_in, const int* in_sizes, int n_in,
                              void* d_out, int out_size, void* d_ws, size_t ws_size,
                              hipStream_t stream)
{
    const float* x  = (const float*)d_in[0];
    const float* Wq = (const float*)d_in[1];
    const float* Wk = (const float*)d_in[2];
    const float* Wv = (const float*)d_in[3];
    const float* Wo = (const float*)d_in[4];
    const float* bo = (const float*)d_in[5];

    // ws (u16 elems): Wqb/Wkb/Wvb 256K ea | Wob 512K | Q,K,V,O 2M ea | Op ns*2M
    // then lbuf (ns*NH*SEQ fp32). xb (bf16 x left half) aliases the O slot:
    // written by convert_w, read by qkv, dead before combine writes O.
    size_t fixed_e = 3 * (size_t)DHALF * DHALF + (size_t)DMODEL * DHALF
                   + 4 * (size_t)SEQ * DHALF;
    size_t need4 = (fixed_e + 4 * (size_t)SEQ * DHALF) * 2
                 + 4 * (size_t)NH * SEQ * 4;
    const int ns = (ws_size >= need4) ? 4 : 2;

    uint16_t* Wqb = (uint16_t*)d_ws;
    uint16_t* Wkb = Wqb + (size_t)DHALF * DHALF;
    uint16_t* Wvb = Wkb + (size_t)DHALF * DHALF;
    uint16_t* Wob = Wvb + (size_t)DHALF * DHALF;
    uint16_t* Q   = Wob + (size_t)DMODEL * DHALF;
    uint16_t* K   = Q + (size_t)SEQ * DHALF;
    uint16_t* V   = K + (size_t)SEQ * DHALF;
    uint16_t* O   = V + (size_t)SEQ * DHALF;
    uint16_t* Op  = O + (size_t)SEQ * DHALF;
    float*  lbuf  = (float*)(Op + (size_t)ns * SEQ * DHALF);
    uint16_t* xb  = O;  // alias: live only convert_w -> qkv

    convert_w<<<1664, 256, 0, stream>>>(Wq, Wk, Wv, Wo, x, Wqb, Wkb, Wvb, Wob, xb);
    qkv_kernel<<<dim3(DHALF / 128, SEQ / 128, 3), 256, 0, stream>>>(
        xb, Wqb, Wkb, Wvb, Q, K, V);
    attn_kernel<<<dim3(SEQ / 128, NH, ns), 256, 0, stream>>>(Q, K, V, Op, lbuf, SEQ / ns);
    combine_kernel<<<1024, 256, 0, stream>>>(Op, lbuf, O, ns);
    outproj_kernel<<<dim3(DMODEL / 128, SEQ / 128), 256, 0, stream>>>(
        O, Wob, bo, (float*)d_out);
}